// Round 2
// baseline (2768.697 us; speedup 1.0000x reference)
//
#include <hip/hip_runtime.h>
#include <math.h>

// ---------------------------------------------------------------------------
// UniPhyFluidScan — min-workspace design (~67 MB of d_ws; XT staged in d_out).
// B=4 T=32 C=8 H=128 W=128, Wf=65. imgs N=128 (conv), spectra IMGS=1024.
//
// Pipeline:
//  setup:  tw[128] (cos,sin of 2*pi*t/128), s3[ci]=sum_co conv3_w, norms=0,
//          gky/gkx/k2 + A[b][c][wf][k] via tiny MLP (layout matches spectra).
//  convs (chunked, 16 imgs/chunk, buffers aliased into Xf region):
//    z1  = conv1(x)+b1
//    gz2 = s3*silu'(conv2(silu(z1))+b2)
//    gz1 = convT2(gz2)*silu'(z1)
//    XT  = x + dt[b]*convT1(gz1)          -> stored in d_out
//  k_fft_fwd (per img, LDS): XT -> Xf[img][wf][k] * (1/128)     (ortho fwd)
//  k_scan_fused (in place): project -> h[t]=A*h+x -> project, norms via atomics
//  k_fft_inv (per img, LDS): h_f * scale -> irfft2 -> d_out     (ortho inv)
//
// Workspace (floats):
//   XFH   @0          17,039,360   (conv chunk bufs alias first 12,582,912)
//   A     @17,039,360    532,480
//   GKY   @17,571,840      8,320
//   GKX   @17,580,160      8,320
//   K2    @17,588,480      8,320
//   TW    @17,596,800        256
//   S3    @17,597,056         16
//   NORMS @17,597,072        256
//   total 17,597,328 floats = 70,389,312 bytes (~67 MB)
// ---------------------------------------------------------------------------

#define CC 8

__device__ __forceinline__ float sig_(float x){ return 1.f/(1.f+expf(-x)); }
__device__ __forceinline__ float dsilu_(float x){ float s = sig_(x); return s*(1.f + x*(1.f-s)); }

// ---------------- setup ----------------------------------------------------
__global__ void k_setup_misc(const float* __restrict__ c3w, float2* __restrict__ tw,
                             float* __restrict__ s3, float* __restrict__ norms){
  int t = threadIdx.x;
  if (t < 128){
    float th = (float)t * 0.04908738521234052f; // 2*pi/128
    tw[t] = make_float2(cosf(th), sinf(th));
  }
  if (t < 16){
    float s = 0.f;
    for (int co=0; co<8; ++co) s += c3w[co*16 + t];
    s3[t] = s;
  }
  norms[t] = 0.f;
}

// one thread per (wf,k): tid = wf*128 + k  (k is the H-frequency index)
__global__ void k_setup_grid(const float* __restrict__ dt, const float* __restrict__ w1,
                             const float* __restrict__ b1, const float* __restrict__ w2,
                             const float* __restrict__ b2,
                             float* __restrict__ gky_a, float* __restrict__ gkx_a,
                             float* __restrict__ k2_a, float2* __restrict__ A){
  int tid = blockIdx.x*blockDim.x + threadIdx.x;
  if (tid >= 65*128) return;
  int wf = tid >> 7, k = tid & 127;
  float ky = (float)(k < 64 ? k : k-128) * (1.f/128.f);
  float kx = (float)wf * (1.f/128.f);
  gky_a[tid] = ky; gkx_a[tid] = kx;
  float k2 = ky*ky + kx*kx;
  k2_a[tid] = (tid==0) ? 1.f : k2;
  float kphys = sqrtf(ky*ky + kx*kx);
  float omega[CC];
  #pragma unroll
  for (int c=0;c<CC;++c) omega[c] = b2[c];
  for (int j=0;j<64;++j){
    float hp = ky*w1[j] + kx*w1[64+j] + b1[j];
    float hv = hp * sig_(hp);
    #pragma unroll
    for (int c=0;c<CC;++c) omega[c] = fmaf(hv, w2[j*CC + c], omega[c]);
  }
  #pragma unroll
  for (int c=0;c<CC;++c) omega[c] += kphys;
  for (int b=0;b<4;++b){
    float d = dt[b];
    #pragma unroll
    for (int c=0;c<CC;++c){
      float ph = omega[c]*d;
      float sn, cs; sincosf(ph, &sn, &cs);
      A[(b*8+c)*8320 + tid] = make_float2(cs, sn);
    }
  }
}

// ---------------- conv family ----------------------------------------------
// Tile 16 rows x 32 cols, block (16,16), 2 px/thread.
// MODE 0: z1 = conv1(x)+b1
// MODE 1: gz2 = s3*silu'(conv2(silu(in))+b2)
// MODE 2: gz1 = convT2(in) * silu'(aux)
// MODE 3: XT  = aux + dt[(nbase+n)/32]*convT1(in)
template<int CIN, int COUT, int MODE>
__global__ __launch_bounds__(256) void k_conv(const float* __restrict__ in,
                                              const float* __restrict__ wsrc,
                                              const float* __restrict__ bias,
                                              const float* __restrict__ aux,
                                              const float* __restrict__ dtp,
                                              float* __restrict__ out,
                                              int nbase){
  __shared__ float s_in[CIN*18*34];
  __shared__ __align__(16) float s_w[CIN*9*COUT];
  int n = blockIdx.z;
  int ox0 = blockIdx.x*32, oy0 = blockIdx.y*16;
  int tx = threadIdx.x, ty = threadIdx.y;
  int tid = ty*16 + tx;

  for (int i=tid; i<CIN*9*COUT; i+=256){
    int co = i % COUT; int r = i / COUT;   // r = ci*9+k
    float wv;
    if constexpr (MODE <= 1){
      wv = wsrc[co*(CIN*9) + r];
    } else {
      int ci = r/9, k = r - ci*9, ky = k/3, kx = k - ky*3;
      wv = wsrc[(ci*COUT+co)*9 + (2-ky)*3 + (2-kx)];
    }
    s_w[i] = wv;
  }
  const float* ip = in + (size_t)n*CIN*16384;
  for (int i=tid; i<CIN*612; i+=256){
    int ci = i/612; int p = i - ci*612; int py = p/34, px = p - py*34;
    int gy = oy0 + py - 1, gx = ox0 + px - 1;
    float v = 0.f;
    if ((unsigned)gy < 128u && (unsigned)gx < 128u) v = ip[(ci*128+gy)*128+gx];
    if constexpr (MODE == 1) v = v * sig_(v);
    s_in[i] = v;
  }
  __syncthreads();

  float a0[COUT], a1[COUT];
  #pragma unroll
  for (int co=0; co<COUT; ++co){
    float b = 0.f;
    if constexpr (MODE <= 1) b = bias[co];
    a0[co] = b; a1[co] = b;
  }
  for (int ci=0; ci<CIN; ++ci){
    const float* si = s_in + ci*612;
    #pragma unroll
    for (int ky=0; ky<3; ++ky){
      #pragma unroll
      for (int kx=0; kx<3; ++kx){
        float v0 = si[(ty+ky)*34 + tx+kx];
        float v1 = si[(ty+ky)*34 + tx+16+kx];
        const float4* wp = (const float4*)(s_w + (ci*9 + ky*3+kx)*COUT);
        #pragma unroll
        for (int q=0; q<COUT/4; ++q){
          float4 wv = wp[q];
          a0[4*q+0] = fmaf(wv.x, v0, a0[4*q+0]); a1[4*q+0] = fmaf(wv.x, v1, a1[4*q+0]);
          a0[4*q+1] = fmaf(wv.y, v0, a0[4*q+1]); a1[4*q+1] = fmaf(wv.y, v1, a1[4*q+1]);
          a0[4*q+2] = fmaf(wv.z, v0, a0[4*q+2]); a1[4*q+2] = fmaf(wv.z, v1, a1[4*q+2]);
          a0[4*q+3] = fmaf(wv.w, v0, a0[4*q+3]); a1[4*q+3] = fmaf(wv.w, v1, a1[4*q+3]);
        }
      }
    }
  }
  int oy = oy0+ty;
  float dtv = 0.f;
  if constexpr (MODE == 3) dtv = dtp[(nbase + n) >> 5];
  #pragma unroll
  for (int co=0; co<COUT; ++co){
    int i0 = ((n*COUT+co)*128+oy)*128 + ox0 + tx;
    int i1 = i0 + 16;
    if constexpr (MODE == 0){
      out[i0] = a0[co]; out[i1] = a1[co];
    } else if constexpr (MODE == 1){
      out[i0] = aux[co]*dsilu_(a0[co]);
      out[i1] = aux[co]*dsilu_(a1[co]);
    } else if constexpr (MODE == 2){
      out[i0] = a0[co]*dsilu_(aux[i0]);
      out[i1] = a1[co]*dsilu_(aux[i1]);
    } else {
      out[i0] = fmaf(dtv, a0[co], aux[i0]);
      out[i1] = fmaf(dtv, a1[co], aux[i1]);
    }
  }
}

// ---------------- fused forward FFT (per image) -----------------------------
// XT[h][w] -> Xf[wf][k] = (1/128) sum_{h,w} x e^{-2pi i (h k + w wf)/128}
__global__ __launch_bounds__(512) void k_fft_fwd(const float* __restrict__ xt,
                                                 const float2* __restrict__ twg,
                                                 float2* __restrict__ X){
  __shared__ float  s_xT[128*129];   // [w][h], pad 129: conflict-free W/R
  __shared__ float2 s_rb[65*128];    // [wf][h]
  __shared__ float2 s_tw[128];
  int img = blockIdx.x;
  int tid = threadIdx.x;
  if (tid < 128) s_tw[tid] = twg[tid];
  const float* xp = xt + (size_t)img*16384;
  for (int i=tid; i<16384; i+=512){
    int h = i>>7, w = i&127;
    s_xT[w*129 + h] = xp[i];         // coalesced global, conflict-free LDS
  }
  __syncthreads();
  // row DFT: lanes share wf -> s_tw broadcast; s_xT stride-1 in h
  for (int i=tid; i<8320; i+=512){
    int wf = i>>7, h = i&127;
    const float* col = s_xT + h;
    float re=0.f, im=0.f; int jj=0;
    for (int w=0; w<128; ++w){
      float x = col[w*129];
      float2 t = s_tw[jj]; jj = (jj+wf)&127;
      re = fmaf(x,  t.x, re);
      im = fmaf(x, -t.y, im);
    }
    s_rb[wf*128 + h] = make_float2(re, im);
  }
  __syncthreads();
  // col DFT: lanes share wf -> s_rb broadcast
  float2* Xp = X + (size_t)img*8320;
  for (int i=tid; i<8320; i+=512){
    int wf = i>>7, k = i&127;
    const float2* rb = s_rb + wf*128;
    float re=0.f, im=0.f; int jj=0;
    for (int h=0; h<128; ++h){
      float2 Xv = rb[h];
      float2 t = s_tw[jj]; jj = (jj+k)&127;
      re += Xv.x*t.x + Xv.y*t.y;
      im += Xv.y*t.x - Xv.x*t.y;
    }
    Xp[i] = make_float2(re*(1.f/128.f), im*(1.f/128.f));  // coalesced
  }
}

// ---------------- fused projection+scan+projection+norms (in place) ---------
// 7 classes: class 0 handles channels {0,1} (projection couples them),
// classes 1..6 handle channel cls+1. 33,280 threads per class.
__global__ __launch_bounds__(256) void k_scan_fused(float2* __restrict__ X,
                                                    const float2* __restrict__ A2,
                                                    const float* __restrict__ gky,
                                                    const float* __restrict__ gkx,
                                                    const float* __restrict__ k2,
                                                    float* __restrict__ norms){
  int tid = blockIdx.x*256 + threadIdx.x;
  int cls = tid / 33280;
  int j   = tid - cls*33280;
  int b   = j / 8320;
  int r   = j - b*8320;           // wf*128 + k
  int lane0 = ((threadIdx.x & 63) == 0);

  if (cls == 0){
    float kyv = gky[r], kxv = gkx[r], ik2 = 1.f/k2[r];
    float2 a0 = A2[(b*8+0)*8320 + r];
    float2 a1 = A2[(b*8+1)*8320 + r];
    float h0r=0.f,h0i=0.f,h1r=0.f,h1i=0.f;
    for (int t=0; t<32; ++t){
      int base = ((b*32+t)*8)*8320 + r;
      float2 u = X[base];
      float2 v = X[base + 8320];
      float dr = (kyv*u.x + kxv*v.x)*ik2;
      float di = (kyv*u.y + kxv*v.y)*ik2;
      float uxr = u.x - kyv*dr, uxi = u.y - kyv*di;
      float vxr = v.x - kxv*dr, vxi = v.y - kxv*di;
      float ni = uxr*uxr + uxi*uxi + vxr*vxr + vxi*vxi;
      float n0r = a0.x*h0r - a0.y*h0i + uxr;
      float n0i = a0.x*h0i + a0.y*h0r + uxi;
      float n1r = a1.x*h1r - a1.y*h1i + vxr;
      float n1i = a1.x*h1i + a1.y*h1r + vxi;
      h0r=n0r; h0i=n0i; h1r=n1r; h1i=n1i;
      float er = (kyv*h0r + kxv*h1r)*ik2;
      float ei = (kyv*h0i + kxv*h1i)*ik2;
      float p0r = h0r - kyv*er, p0i = h0i - kyv*ei;
      float p1r = h1r - kxv*er, p1i = h1i - kxv*ei;
      float no = p0r*p0r + p0i*p0i + p1r*p1r + p1i*p1i;
      X[base]        = make_float2(p0r, p0i);
      X[base + 8320] = make_float2(p1r, p1i);
      #pragma unroll
      for (int off=32; off; off>>=1){ ni += __shfl_down(ni, off); no += __shfl_down(no, off); }
      if (lane0){ atomicAdd(&norms[(b*32+t)*2], ni); atomicAdd(&norms[(b*32+t)*2+1], no); }
    }
  } else {
    int c = cls + 1;
    float2 a = A2[(b*8+c)*8320 + r];
    float hr=0.f, hi=0.f;
    for (int t=0; t<32; ++t){
      int base = ((b*32+t)*8 + c)*8320 + r;
      float2 x = X[base];
      float ni = x.x*x.x + x.y*x.y;
      float nr = a.x*hr - a.y*hi + x.x;
      float nn = a.x*hi + a.y*hr + x.y;
      hr=nr; hi=nn;
      float no = hr*hr + hi*hi;
      X[base] = make_float2(hr, hi);
      #pragma unroll
      for (int off=32; off; off>>=1){ ni += __shfl_down(ni, off); no += __shfl_down(no, off); }
      if (lane0){ atomicAdd(&norms[(b*32+t)*2], ni); atomicAdd(&norms[(b*32+t)*2+1], no); }
    }
  }
}

// ---------------- fused inverse FFT (per image) -----------------------------
__global__ __launch_bounds__(512) void k_fft_inv(const float2* __restrict__ X,
                                                 const float2* __restrict__ twg,
                                                 const float* __restrict__ norms,
                                                 float* __restrict__ out){
  __shared__ float2 s_hf[65*128];    // [wf][k]
  __shared__ float2 s_cb[65*128];    // [wf][h]
  __shared__ float2 s_tw[128];
  int img = blockIdx.x;
  int tid = threadIdx.x;
  if (tid < 128) s_tw[tid] = twg[tid];
  const float2* Xp = X + (size_t)img*8320;
  for (int i=tid; i<8320; i+=512) s_hf[i] = Xp[i];
  __syncthreads();
  int bt = img >> 3;
  float scale = sqrtf(norms[bt*2]) / (sqrtf(norms[bt*2+1]) + 1e-6f) * (1.f/128.f);
  // inverse col DFT: cb[h][wf] = scale * sum_k hf[wf][k] e^{+2pi i h k/128}
  for (int i=tid; i<8320; i+=512){
    int wf = i>>7, h = i&127;
    const float2* col = s_hf + wf*128;
    float re=0.f, im=0.f; int jj=0;
    for (int k=0; k<128; ++k){
      float2 Xv = col[k];
      float2 t = s_tw[jj]; jj = (jj+h)&127;
      re += Xv.x*t.x - Xv.y*t.y;
      im += Xv.x*t.y + Xv.y*t.x;
    }
    s_cb[wf*128 + h] = make_float2(re*scale, im*scale);
  }
  __syncthreads();
  // Hermitian c2r row pass (Im of wf=0 and wf=64 dropped, FFTW semantics)
  float* op = out + (size_t)img*16384;
  for (int i=tid; i<16384; i+=512){
    int h = i>>7, w = i&127;
    float acc = s_cb[h].x + ((w&1) ? -s_cb[64*128+h].x : s_cb[64*128+h].x);
    int jj = 0;
    for (int wf=1; wf<64; ++wf){
      jj = (jj + w)&127;
      float2 Xv = s_cb[wf*128 + h];
      float2 t = s_tw[jj];
      acc = fmaf(2.f, Xv.x*t.x - Xv.y*t.y, acc);
    }
    op[i] = acc;
  }
}

// ---------------------------------------------------------------------------
extern "C" void kernel_launch(void* const* d_in, const int* in_sizes, int n_in,
                              void* d_out, int out_size, void* d_ws, size_t ws_size,
                              hipStream_t stream) {
  const float* x_seq = (const float*)d_in[0];
  const float* dt    = (const float*)d_in[1];
  const float* pw1   = (const float*)d_in[2];
  const float* pb1   = (const float*)d_in[3];
  const float* pw2   = (const float*)d_in[4];
  const float* pb2   = (const float*)d_in[5];
  const float* c1w   = (const float*)d_in[6];
  const float* c1b   = (const float*)d_in[7];
  const float* c2w   = (const float*)d_in[8];
  const float* c2b   = (const float*)d_in[9];
  const float* c3w   = (const float*)d_in[10];
  float* out = (float*)d_out;
  float* ws  = (float*)d_ws;

  float*  XFHf = ws;                        // 17,039,360 floats
  float*  Aa   = ws + 17039360;             // 532,480
  float*  GKY  = ws + 17571840;             // 8,320
  float*  GKX  = ws + 17580160;             // 8,320
  float*  K2   = ws + 17588480;             // 8,320
  float*  TWf  = ws + 17596800;             // 256
  float*  S3   = ws + 17597056;             // 16
  float*  NORMS= ws + 17597072;             // 256

  float2* XFH = (float2*)XFHf;
  float2* TW2 = (float2*)TWf;
  float2* A2  = (float2*)Aa;

  // conv chunk buffers alias the (not yet live) XFH region
  float* CZ1  = XFHf;
  float* CGZ2 = XFHf + 4194304;
  float* CGZ1 = XFHf + 8388608;

  k_setup_misc<<<1, 256, 0, stream>>>(c3w, TW2, S3, NORMS);
  k_setup_grid<<<33, 256, 0, stream>>>(dt, pw1, pb1, pw2, pb2, GKY, GKX, K2, A2);

  dim3 cb(16,16), cg(4,8,16);
  for (int n0 = 0; n0 < 128; n0 += 16){
    const float* xin = x_seq + (size_t)n0*8*16384;
    float*       xtp = out   + (size_t)n0*8*16384;   // XT staged in d_out
    k_conv<8,16,0><<<cg, cb, 0, stream>>>(xin, c1w, c1b, nullptr, nullptr, CZ1, n0);
    k_conv<16,16,1><<<cg, cb, 0, stream>>>(CZ1, c2w, c2b, S3, nullptr, CGZ2, n0);
    k_conv<16,16,2><<<cg, cb, 0, stream>>>(CGZ2, c2w, nullptr, CZ1, nullptr, CGZ1, n0);
    k_conv<16,8,3><<<cg, cb, 0, stream>>>(CGZ1, c1w, nullptr, xin, dt, xtp, n0);
  }

  k_fft_fwd<<<1024, 512, 0, stream>>>(out, TW2, XFH);
  k_scan_fused<<<910, 256, 0, stream>>>(XFH, A2, GKY, GKX, K2, NORMS);
  k_fft_inv<<<1024, 512, 0, stream>>>(XFH, TW2, NORMS, out);
}